// Round 13
// baseline (126.132 us; speedup 1.0000x reference)
//
#include <hip/hip_runtime.h>
#include <hip/hip_bf16.h>
#include <math.h>

#define B_      8
#define CIN     256
#define CMID    512
#define COUT    256
#define N_      2048
#define SCALE_  10.0f
#define EPS_THR 1e-3f
#define NORM_EPS_ 1e-12f

typedef __attribute__((ext_vector_type(8))) short short8;
typedef __attribute__((ext_vector_type(4))) float f32x4;

__device__ __forceinline__ ushort f2bf(float x) {
    union { float f; uint u; } v; v.f = x;
    uint r = v.u + 0x7FFF + ((v.u >> 16) & 1);
    return (ushort)(r >> 16);
}
__device__ __forceinline__ void gload_lds16(const void* g, void* l) {
    __builtin_amdgcn_global_load_lds((const __attribute__((address_space(1))) void*)g,
                                     (__attribute__((address_space(3))) void*)l, 16, 0, 0);
}

// ---------------- K0: weights fp32 -> bf16 ------------------------------------------
__global__ __launch_bounds__(256) void prep_w(const float* __restrict__ W1,
                                              const float* __restrict__ W2,
                                              ushort* __restrict__ W1b,
                                              ushort* __restrict__ W2b) {
    int idx = blockIdx.x * 256 + threadIdx.x;   // 0..131071
    W1b[idx] = f2bf(W1[idx]);
    W2b[idx] = f2bf(W2[idx]);
}

// ---------------- K1: conv1 fused with input transpose + key tail copy --------------
#define ASTRIDE 40
__global__ __launch_bounds__(512) void conv1_fused(const float* __restrict__ q,
                                                   const float* __restrict__ k,
                                                   const ushort* __restrict__ W1b,
                                                   ushort* __restrict__ H,
                                                   float* __restrict__ tail) {
    __shared__ ushort As[64 * ASTRIDE];   // 5 KB, padded stride
    __shared__ ushort Bs[512 * 32];       // 32 KB
    int tid = threadIdx.x;
    int lane = tid & 63, wave = tid >> 6;
    int g = lane >> 4, cl = lane & 15;
    // XCD-aligned tile permutation
    int bx = blockIdx.x;
    int half = bx >> 8;
    int u = bx & 255;
    int pb = u & 7, pj = u >> 3;          // pj in [0,32)
    size_t m0 = ((size_t)half * 256 + (size_t)pb * 32 + pj) * 64;
    const int is_k = (m0 >= 16384);
    const float* xsrc = is_k ? k : q;
    int b = (int)((m0 >> 11) & 7);
    int nbase = (int)(m0 & 2047);
    const size_t xoff = ((size_t)b * CIN + wave * 4) * N_ + nbase + lane;
    const float* xp = xsrc + xoff;

    f32x4 acc[4][4];
#pragma unroll
    for (int i = 0; i < 4; ++i)
#pragma unroll
        for (int j = 0; j < 4; ++j) acc[i][j] = (f32x4)0.f;

    for (int k0 = 0; k0 < CIN; k0 += 32) {
#pragma unroll
        for (int si = 0; si < 4; ++si) {
            int s = tid + si * 512;
            gload_lds16(W1b + (size_t)(s >> 2) * CIN + k0 + (s & 3) * 8, Bs + s * 8);
        }
        float v0 = xp[(size_t)(k0 + 0) * N_];
        float v1 = xp[(size_t)(k0 + 1) * N_];
        float v2 = xp[(size_t)(k0 + 2) * N_];
        float v3 = xp[(size_t)(k0 + 3) * N_];
        if (is_k) {   // fused key->output-tail copy (same bytes, same layout)
            __builtin_nontemporal_store(v0, tail + xoff + (size_t)(k0 + 0) * N_);
            __builtin_nontemporal_store(v1, tail + xoff + (size_t)(k0 + 1) * N_);
            __builtin_nontemporal_store(v2, tail + xoff + (size_t)(k0 + 2) * N_);
            __builtin_nontemporal_store(v3, tail + xoff + (size_t)(k0 + 3) * N_);
        }
        ushort4 wv;
        wv.x = f2bf(v0); wv.y = f2bf(v1); wv.z = f2bf(v2); wv.w = f2bf(v3);
        *(ushort4*)&As[lane * ASTRIDE + wave * 4] = wv;
        __syncthreads();

        short8 af[4], bfr[4];
#pragma unroll
        for (int mi = 0; mi < 4; ++mi)
            af[mi] = *(const short8*)&As[(mi * 16 + cl) * ASTRIDE + g * 8];
#pragma unroll
        for (int ni = 0; ni < 4; ++ni)
            bfr[ni] = *(const short8*)&Bs[(wave * 64 + ni * 16 + cl) * 32 + g * 8];
#pragma unroll
        for (int mi = 0; mi < 4; ++mi)
#pragma unroll
            for (int ni = 0; ni < 4; ++ni)
                acc[mi][ni] = __builtin_amdgcn_mfma_f32_16x16x32_bf16(af[mi], bfr[ni], acc[mi][ni], 0, 0, 0);
        __syncthreads();
    }

#pragma unroll
    for (int mi = 0; mi < 4; ++mi)
#pragma unroll
        for (int ni = 0; ni < 4; ++ni)
#pragma unroll
            for (int r = 0; r < 4; ++r) {
                float v = acc[mi][ni][r];
                v = (v >= 0.f) ? v : 0.01f * v;
                H[(m0 + mi * 16 + g * 4 + r) * CMID + wave * 64 + ni * 16 + cl] = f2bf(v);
            }
}

// ---------------- K2: conv2 fused with row L2-norm ----------------------------------
// Output QK in MFMA-FRAGMENT layout: element (row, kcol) stored at
//   (row>>4)*4096 + (kcol>>5)*512 + ((kcol>>3)&3)*128 + (row&15)*8 + (kcol&7)
__global__ __launch_bounds__(512) void conv2_norm(const ushort* __restrict__ H,
                                                  const ushort* __restrict__ W2b,
                                                  ushort* __restrict__ QK) {
    __shared__ ushort As[128 * 32];   // 8 KB
    __shared__ ushort Bs[256 * 32];   // 16 KB
    __shared__ float red[4][128];     // 2 KB
    int tid = threadIdx.x;
    int lane = tid & 63, wave = tid >> 6;
    int wm = wave >> 2, wn = wave & 3;
    int g = lane >> 4, cl = lane & 15;
    int bx = blockIdx.x;
    int half = bx >> 7;
    int u = bx & 127;
    int pb = u & 7, pj = u >> 3;          // pj in [0,16)
    size_t m0 = ((size_t)half * 128 + (size_t)pb * 16 + pj) * 128;

    f32x4 acc[4][4];
#pragma unroll
    for (int i = 0; i < 4; ++i)
#pragma unroll
        for (int j = 0; j < 4; ++j) acc[i][j] = (f32x4)0.f;

    for (int k0 = 0; k0 < CMID; k0 += 32) {
        gload_lds16(H + (m0 + (tid >> 2)) * CMID + k0 + (tid & 3) * 8, As + tid * 8);
#pragma unroll
        for (int si = 0; si < 2; ++si) {
            int s = tid + si * 512;
            gload_lds16(W2b + (size_t)(s >> 2) * CMID + k0 + (s & 3) * 8, Bs + s * 8);
        }
        __syncthreads();
        short8 af[4], bfr[4];
#pragma unroll
        for (int mi = 0; mi < 4; ++mi)
            af[mi] = *(const short8*)&As[(wm * 64 + mi * 16 + cl) * 32 + g * 8];
#pragma unroll
        for (int ni = 0; ni < 4; ++ni)
            bfr[ni] = *(const short8*)&Bs[(wn * 64 + ni * 16 + cl) * 32 + g * 8];
#pragma unroll
        for (int mi = 0; mi < 4; ++mi)
#pragma unroll
            for (int ni = 0; ni < 4; ++ni)
                acc[mi][ni] = __builtin_amdgcn_mfma_f32_16x16x32_bf16(af[mi], bfr[ni], acc[mi][ni], 0, 0, 0);
        __syncthreads();
    }

#pragma unroll
    for (int mi = 0; mi < 4; ++mi)
#pragma unroll
        for (int r = 0; r < 4; ++r) {
            float s = 0.f;
#pragma unroll
            for (int ni = 0; ni < 4; ++ni) { float v = acc[mi][ni][r]; s += v * v; }
#pragma unroll
            for (int off = 1; off < 16; off <<= 1) s += __shfl_xor(s, off, 64);
            if (cl == 0) red[wn][wm * 64 + mi * 16 + g * 4 + r] = s;
        }
    __syncthreads();
#pragma unroll
    for (int mi = 0; mi < 4; ++mi)
#pragma unroll
        for (int r = 0; r < 4; ++r) {
            int row = wm * 64 + mi * 16 + g * 4 + r;
            size_t row_g = m0 + row;
            float tot = red[0][row] + red[1][row] + red[2][row] + red[3][row];
            float inv = 1.0f / fmaxf(sqrtf(tot), NORM_EPS_);
            size_t pbase = (row_g >> 4) * 4096 + (size_t)(row_g & 15) * 8;
#pragma unroll
            for (int ni = 0; ni < 4; ++ni) {
                int kcol = wn * 64 + ni * 16 + cl;
                size_t off = pbase + (size_t)(kcol >> 5) * 512
                           + (size_t)((kcol >> 3) & 3) * 128 + (kcol & 7);
                QK[off] = f2bf(acc[mi][ni][r] * inv);
            }
        }
}

// ---------------- K3: fused scores + softmax(fixed max) + threshold -----------------
// Two-pass recompute, 64 q-rows x 2048 k-cols per block, grid 256 (1 block/CU).
// Q-tile (4 fragment panels = 32 KB) staged in LDS via linear gload_lds; af read
// per-use with conflict-free ds_read_b128 => per-thread live set ~110 VGPR (R8's
// spill cause removed). Pass 1: K-panel stream -> row sums. Pass 2: re-stream
// (XCD-L2-hot), recompute, scale, threshold, store — stores overlap reads/MFMA.
__global__ __launch_bounds__(512, 2) void scores_softmax(const ushort* __restrict__ QK,
                                                         float* __restrict__ out) {
    __shared__ ushort Qs[4 * 4096];   // 32 KB
    __shared__ float red[8][64];      // 2 KB
    int bid = blockIdx.x;
    int b = bid & 7;                  // batch-per-XCD swizzle (256 blocks, 32/XCD)
    int m0 = (bid >> 3) * 64;
    int tid = threadIdx.x;
    int lane = tid & 63, wave = tid >> 6;
    int g = lane >> 4, cl = lane & 15;

    const ushort* Qp = QK + ((size_t)(b * N_ + m0) >> 4) * 4096;  // 4 contiguous panels
#pragma unroll
    for (int s = 0; s < 4; ++s)
        gload_lds16(Qp + (size_t)(s * 512 + tid) * 8, Qs + (size_t)(s * 512 + tid) * 8);

    const ushort* Kf = QK + ((size_t)(16384 + b * N_ + wave * 256) >> 4) * 4096;
    __syncthreads();   // Q staged (compiler drains vmcnt before barrier)

    float rs[4][4];
#pragma unroll
    for (int mi = 0; mi < 4; ++mi)
#pragma unroll
        for (int r = 0; r < 4; ++r) rs[mi][r] = 0.f;

    // ---- pass 1: row sums only ----
    for (int ct = 0; ct < 16; ++ct) {
        short8 bfr[8];
#pragma unroll
        for (int ks = 0; ks < 8; ++ks)
            bfr[ks] = *(const short8*)(Kf + (size_t)ct * 4096 + ks * 512 + lane * 8);
        f32x4 a[4];
#pragma unroll
        for (int mi = 0; mi < 4; ++mi) a[mi] = (f32x4)0.f;
#pragma unroll
        for (int ks = 0; ks < 8; ++ks)
#pragma unroll
            for (int mi = 0; mi < 4; ++mi) {
                short8 af = *(const short8*)&Qs[mi * 4096 + ks * 512 + lane * 8];
                a[mi] = __builtin_amdgcn_mfma_f32_16x16x32_bf16(af, bfr[ks], a[mi], 0, 0, 0);
            }
#pragma unroll
        for (int mi = 0; mi < 4; ++mi)
#pragma unroll
            for (int r = 0; r < 4; ++r)
                rs[mi][r] += __expf((a[mi][r] - 1.0f) * SCALE_);
    }

    // reduce over 16 cl lanes, then across 8 waves via LDS
#pragma unroll
    for (int mi = 0; mi < 4; ++mi)
#pragma unroll
        for (int r = 0; r < 4; ++r) {
            float s = rs[mi][r];
#pragma unroll
            for (int off = 1; off < 16; off <<= 1) s += __shfl_xor(s, off, 64);
            if (cl == 0) red[wave][mi * 16 + g * 4 + r] = s;
        }
    __syncthreads();

    float inv_[4][4];
#pragma unroll
    for (int mi = 0; mi < 4; ++mi)
#pragma unroll
        for (int r = 0; r < 4; ++r) {
            int row = mi * 16 + g * 4 + r;
            float t = 0.f;
#pragma unroll
            for (int w = 0; w < 8; ++w) t += red[w][row];
            inv_[mi][r] = 1.0f / t;
        }

    // ---- pass 2: recompute (K-panel L2-hot), scale, threshold, store ----
    float* ob = out + ((size_t)b * N_ + m0) * N_ + wave * 256;
    for (int ct = 0; ct < 16; ++ct) {
        short8 bfr[8];
#pragma unroll
        for (int ks = 0; ks < 8; ++ks)
            bfr[ks] = *(const short8*)(Kf + (size_t)ct * 4096 + ks * 512 + lane * 8);
        f32x4 a[4];
#pragma unroll
        for (int mi = 0; mi < 4; ++mi) a[mi] = (f32x4)0.f;
#pragma unroll
        for (int ks = 0; ks < 8; ++ks)
#pragma unroll
            for (int mi = 0; mi < 4; ++mi) {
                short8 af = *(const short8*)&Qs[mi * 4096 + ks * 512 + lane * 8];
                a[mi] = __builtin_amdgcn_mfma_f32_16x16x32_bf16(af, bfr[ks], a[mi], 0, 0, 0);
            }
#pragma unroll
        for (int mi = 0; mi < 4; ++mi)
#pragma unroll
            for (int r = 0; r < 4; ++r) {
                float w = __expf((a[mi][r] - 1.0f) * SCALE_) * inv_[mi][r];
                w = (w > EPS_THR) ? w : 0.f;
                __builtin_nontemporal_store(w, &ob[(size_t)(mi * 16 + g * 4 + r) * N_ + ct * 16 + cl]);
            }
    }
}

extern "C" void kernel_launch(void* const* d_in, const int* in_sizes, int n_in,
                              void* d_out, int out_size, void* d_ws, size_t ws_size,
                              hipStream_t stream) {
    const float* q  = (const float*)d_in[0];
    const float* k  = (const float*)d_in[1];
    const float* W1 = (const float*)d_in[2];
    const float* W2 = (const float*)d_in[3];
    float* out = (float*)d_out;

    // ws: W1b | W2b | QK  (17.3 MB)
    ushort* W1b = (ushort*)d_ws;
    ushort* W2b = W1b + 131072;
    ushort* QK  = W2b + 131072;                 // [2048 panels][4096] bf16 (fragment layout)

    // H scratch inside d_out (overwritten by scores_softmax later)
    ushort* H = (ushort*)d_out;                 // [32768][512] bf16, 33.5 MB
    float* tail = out + (size_t)B_ * N_ * N_;   // key copy destination

    prep_w<<<512, 256, 0, stream>>>(W1, W2, W1b, W2b);
    conv1_fused<<<512, 512, 0, stream>>>(q, k, W1b, H, tail);
    conv2_norm<<<256, 512, 0, stream>>>(H, W2b, QK);
    scores_softmax<<<256, 512, 0, stream>>>(QK, out);
}